// Round 6
// baseline (835.006 us; speedup 1.0000x reference)
//
#include <hip/hip_runtime.h>

// Fused AttentionAggregator: B=4096, N=64, F=128, H=8, D=64, HD=512.
// out[b,n,c] = relu(lin[b,n,c] * softmax_n(leakyrelu(att))[b, c/64, n])
// lin = x @ W_lin via fp16 MFMA (operand-swapped: A=W cols, B=x rows).
// lin stays register-resident; att partials feed the phase-B accumulator
// directly into mfma_f32_16x16x16_f16 as the B-operand.
//
// R6: persistent blocks (grid 1024, NBATCH=4) with ZERO-VGPR cross-batch
// prefetch: x staged fp32 via global_load_lds (16 B DMA) into a double-
// buffered LDS tile, source pre-XOR-swizzled (16-B chunks within 128-B
// lines, banks provably uniform on GEMM reads) -- R1's reg-parked prefetch
// spilled; DMA can't. cvt fp32->f16 moved inline into the B-fragment read
// (bit-identical). attbuf+reduction replaced by ds_add_f32 into a double-
// buffered 64x17 accumulator: 2 barriers/iter (r0 had 4). ftile aliases the
// dead xs[cur]. LDS 78592 B -> still 2 blocks/CU.

typedef _Float16 half8  __attribute__((ext_vector_type(8)));
typedef _Float16 half4v __attribute__((ext_vector_type(4)));
typedef float    f32x4  __attribute__((ext_vector_type(4)));

static constexpr int NSEQ   = 64;
static constexpr int FIN    = 128;
static constexpr int HDIM   = 512;   // H*D
static constexpr int NHEAD  = 8;
static constexpr int NBATCH = 4;     // batches per persistent block
static constexpr int AA_LD  = 17;    // att accumulator row stride (odd -> 16 banks)

// smem blob (byte offsets):
//   [0, 32768)       xs0: x f32 [64][128], 16B-chunk swizzled
//   [32768, 65536)   xs1: double buffer
//   [65536, 69888)   ft7: wave-7 ftile [16][68] f32 (waves 0-6 alias xs[cur])
static constexpr int XS_B       = 32768;
static constexpr int FT7_OFF    = 65536;
static constexpr int BLOB_BYTES = 69888;

typedef const __attribute__((address_space(1))) unsigned int* gas_ptr;
typedef __attribute__((address_space(3))) unsigned int*       las_ptr;

__device__ __forceinline__ void gload_lds16(const void* g, void* l)
{
    __builtin_amdgcn_global_load_lds((gas_ptr)g, (las_ptr)l, 16, 0, 0);
}

// Prep: W_lin (fp32 [128][512]) -> W_linT fp16 [512][128] (k-contiguous);
//       W_att (fp32 [1024][8])  -> waA fp16 [8192]: A-fragment-ordered Wa_cat.
//       Wa_cat[c][j]: j in [0,8)  = W_att[512+c][j]   (lin term)
//                     j in [8,16) = W_att[c][j-8]     (src term)
__global__ __launch_bounds__(256) void prep_kernel(const float* __restrict__ wlin,
                                                   const float* __restrict__ watt,
                                                   _Float16* __restrict__ wlinT,
                                                   _Float16* __restrict__ waA)
{
    int t = blockIdx.x * 256 + threadIdx.x;
    if (t < HDIM * FIN) {
        int c = t >> 7;
        int k = t & 127;
        wlinT[t] = (_Float16)wlin[k * HDIM + c];
    }
    if (t < 16 * HDIM) {                 // 8192 waA halves
        int i     = t & 3;
        int lane  = (t >> 2) & 63;
        int slice = t >> 8;              // w*4 + mt, 0..31
        int c = (slice >> 2) * 64 + (slice & 3) * 16 + (lane >> 4) * 4 + i;
        int j = lane & 15;
        float v = (j < NHEAD) ? watt[(HDIM + c) * NHEAD + j]
                              : watt[c * NHEAD + (j - NHEAD)];
        waA[t] = (_Float16)v;
    }
}

__global__ __launch_bounds__(512, 4) void fused_kernel(const float* __restrict__ x,
                                                       const _Float16* __restrict__ wlinT,
                                                       const _Float16* __restrict__ waA,
                                                       const int* __restrict__ mask,
                                                       float* __restrict__ out)
{
    __shared__ char  smem[BLOB_BYTES] __attribute__((aligned(16)));
    __shared__ float att_acc_s[2][NSEQ * AA_LD];   // double-buffered logit accumulator

    const int t    = threadIdx.x;
    const int lane = t & 63;
    const int w    = t >> 6;       // wave 0..7 == head
    const int l15  = lane & 15;
    const int quad = lane >> 4;    // 0..3

    const int b0 = blockIdx.x * NBATCH;

    // zero both att accumulators (rows 0..63, cols 0..15)
    {
        int p0 = t, p1 = t + 512;
        att_acc_s[0][(p0 >> 4) * AA_LD + (p0 & 15)] = 0.f;
        att_acc_s[0][(p1 >> 4) * AA_LD + (p1 & 15)] = 0.f;
        att_acc_s[1][(p0 >> 4) * AA_LD + (p0 & 15)] = 0.f;
        att_acc_s[1][(p1 >> 4) * AA_LD + (p1 & 15)] = 0.f;
    }

    // prologue: DMA-stage batch b0 -> xs0. LDS dest linear (wave base + lane*16);
    // source pre-swizzled: chunk L goes to LDS[L], data from x[L ^ ((row&7)<<4)].
    {
        const char* xg = (const char*)(x + (size_t)b0 * (NSEQ * FIN));
        #pragma unroll
        for (int j = 0; j < 4; ++j) {
            int ci = j * 512 + t;              // 16-B chunk index
            int L  = ci * 16;                  // linear LDS byte offset
            int sw = ((ci >> 5) & 7) << 4;     // row = ci>>5 (512-B rows)
            gload_lds16(xg + (L ^ sw), smem + L);
        }
    }
    __syncthreads();   // drains DMA (vmcnt) + zero-writes

    #pragma unroll 1
    for (int it = 0; it < NBATCH; ++it) {
        const int b   = b0 + it;
        const int cur = it & 1;
        char*  xc = smem + cur * XS_B;
        float* aa = att_acc_s[cur];

        // prefetch next batch into the other buffer; guaranteed landed by
        // barrier (1) (__syncthreads drains vmcnt). No VGPRs held.
        if (it + 1 < NBATCH) {
            const char* xg = (const char*)(x + (size_t)(b + 1) * (NSEQ * FIN));
            char* xn = smem + (cur ^ 1) * XS_B;
            #pragma unroll
            for (int j = 0; j < 4; ++j) {
                int ci = j * 512 + t;
                int L  = ci * 16;
                int sw = ((ci >> 5) & 7) << 4;
                gload_lds16(xg + (L ^ sw), xn + L);
            }
        }
        const int mv = mask[b * NSEQ + lane];

        // ---- Phase B: lin^T GEMM. B-fragment read fp32 from swizzled LDS,
        //      cvt->f16 inline (same rounding as the old staged-f16 path).
        //      acc[mt][nt] reg i: lin[n = nt*16+l15][c = 64w + mt*16 + quad*4 + i]
        f32x4 acc[4][4];
        #pragma unroll
        for (int mt = 0; mt < 4; ++mt)
            #pragma unroll
            for (int nt = 0; nt < 4; ++nt)
                acc[mt][nt] = (f32x4){0.f, 0.f, 0.f, 0.f};

        const int colbase = w * 64;
        #pragma unroll
        for (int ks = 0; ks < 4; ++ks) {
            const int k0 = ks * 32 + quad * 8;     // float index within row
            const int cb = k0 * 4;                 // byte offset within row
            half8 a[4];
            #pragma unroll
            for (int mt = 0; mt < 4; ++mt)
                a[mt] = *(const half8*)(wlinT + (colbase + mt * 16 + l15) * FIN + k0);
            #pragma unroll
            for (int nt = 0; nt < 4; ++nt) {
                const int n  = nt * 16 + l15;
                const int sw = (n & 7) << 4;
                const char* rb = xc + n * 512;
                f32x4 v0 = *(const f32x4*)(rb + (cb ^ sw));
                f32x4 v1 = *(const f32x4*)(rb + ((cb + 16) ^ sw));
                half8 bfr;
                bfr[0] = (_Float16)v0[0]; bfr[1] = (_Float16)v0[1];
                bfr[2] = (_Float16)v0[2]; bfr[3] = (_Float16)v0[3];
                bfr[4] = (_Float16)v1[0]; bfr[5] = (_Float16)v1[1];
                bfr[6] = (_Float16)v1[2]; bfr[7] = (_Float16)v1[3];
                #pragma unroll
                for (int mt = 0; mt < 4; ++mt)
                    acc[mt][nt] = __builtin_amdgcn_mfma_f32_16x16x32_f16(a[mt], bfr, acc[mt][nt], 0, 0, 0);
            }
        }

        // ---- Phase D: att partials via 16x16x16 MFMA, accumulated across
        //      waves directly with ds_add_f32 (replaces attbuf + reduction).
        //      T[nt] C-layout: row j = quad*4+i, col n = nt*16+l15.
        {
            f32x4 T[4];
            #pragma unroll
            for (int nt = 0; nt < 4; ++nt) T[nt] = (f32x4){0.f, 0.f, 0.f, 0.f};
            #pragma unroll
            for (int mt = 0; mt < 4; ++mt) {
                half4v aF = *(const half4v*)(waA + ((w * 4 + mt) * 64 + lane) * 4);
                #pragma unroll
                for (int nt = 0; nt < 4; ++nt) {
                    half4v bF;
                    #pragma unroll
                    for (int i = 0; i < 4; ++i) bF[i] = (_Float16)acc[mt][nt][i];
                    T[nt] = __builtin_amdgcn_mfma_f32_16x16x16f16(aF, bF, T[nt], 0, 0, 0);
                }
            }
            #pragma unroll
            for (int nt = 0; nt < 4; ++nt) {
                const int n = nt * 16 + l15;
                #pragma unroll
                for (int i = 0; i < 4; ++i)
                    atomicAdd(&aa[n * AA_LD + quad * 4 + i], T[nt][i]);
            }
        }
        __syncthreads();   // (1) all ds_adds done; prefetch DMA landed

        // clear the OTHER accumulator for the next iteration (its readers
        // finished before the previous end-of-iteration barrier)
        {
            float* ao = att_acc_s[cur ^ 1];
            int p0 = t, p1 = t + 512;
            ao[(p0 >> 4) * AA_LD + (p0 & 15)] = 0.f;
            ao[(p1 >> 4) * AA_LD + (p1 & 15)] = 0.f;
        }

        // ---- Phase E: leakyrelu + mask + softmax over n; wave w == head w; lane = n
        float aw_reg;
        {
            const float pen = (mv == 0) ? -1e9f : 0.0f;
            float a = aa[lane * AA_LD + w] + aa[8 + w];   // lin term + src term (n=0)
            a = (a >= 0.0f) ? a : 0.2f * a;               // leakyrelu BEFORE mask
            a += pen;
            float mx = a;
            #pragma unroll
            for (int off = 32; off > 0; off >>= 1)
                mx = fmaxf(mx, __shfl_xor(mx, off, 64));
            float e = __expf(a - mx);
            float s = e;
            #pragma unroll
            for (int off = 32; off > 0; off >>= 1)
                s += __shfl_xor(s, off, 64);
            aw_reg = e / s;                               // aw[w][lane]
        }

        // ---- Phase F: out = relu(lin * aw) via per-wave LDS tile transpose:
        //      256-B contiguous row segments -> full-line NT stores.
        //      Waves 0-6 alias the dead xs[cur]; wave 7 uses ft7.
        {
            float* ft = (w < 7) ? (float*)xc + w * (16 * 68)
                                : (float*)(smem + FT7_OFF);
            float* outb = out + (size_t)b * (NSEQ * HDIM);
            #pragma unroll
            for (int nt = 0; nt < 4; ++nt) {
                float awv = __shfl(aw_reg, nt * 16 + l15, 64);  // aw[w][n]
                #pragma unroll
                for (int mt = 0; mt < 4; ++mt) {
                    f32x4 o;
                    #pragma unroll
                    for (int i = 0; i < 4; ++i)
                        o[i] = fmaxf(acc[mt][nt][i] * awv, 0.0f);
                    *(f32x4*)(ft + l15 * 68 + mt * 16 + quad * 4) = o;
                }
                #pragma unroll
                for (int s = 0; s < 4; ++s) {
                    int r = s * 4 + quad;                  // n_local
                    f32x4 v = *(const f32x4*)(ft + r * 68 + l15 * 4);
                    int n = nt * 16 + r;
                    __builtin_nontemporal_store(v, (f32x4*)(outb + n * HDIM + w * 64 + l15 * 4));
                }
            }
        }
        __syncthreads();   // (2) end of iter: ftile reads + clear done;
                           //     xs[cur] safe to DMA-overwrite next iter
    }
}

extern "C" void kernel_launch(void* const* d_in, const int* in_sizes, int n_in,
                              void* d_out, int out_size, void* d_ws, size_t ws_size,
                              hipStream_t stream)
{
    const float* x    = (const float*)d_in[0];
    const float* wlin = (const float*)d_in[1];
    const float* watt = (const float*)d_in[2];
    const int*   mask = (const int*)d_in[3];
    float* out = (float*)d_out;

    _Float16* wlinT = (_Float16*)d_ws;             // 65536 halves = 128 KiB
    _Float16* waA   = wlinT + HDIM * FIN;          // 8192 halves = 16 KiB

    const int B = in_sizes[0] / (NSEQ * FIN);      // 4096

    prep_kernel<<<256, 256, 0, stream>>>(wlin, watt, wlinT, waA);
    fused_kernel<<<B / NBATCH, 512, 0, stream>>>(x, wlinT, waA, mask, out);
}